// Round 12
// baseline (218.141 us; speedup 1.0000x reference)
//
#include <hip/hip_runtime.h>
#include <math.h>

// QuanvolutionHybridGraphQL:
//   q   = cos(2x2 patches of 28x28 img)            -> (B,196,4)
//   qn  = q / (||q||_2 + 1e-12)
//   fid = (qn . qn^T)^2                             -> (B,196,196)
//   adj = fid>=0.8 ? 1 : fid>=0.5 ? 0.5 : 0 ; diag=0
//   logits = (mean_n q @ W1 + b1) @ W2 + b2         -> (B,10)
// adj 629MB fp32, HBM-write bound. Fill (plain, grid-stride) = 6.6 TB/s.
// Ladder: R3 NT 140 | R7 NT aligned 137.5 | R8/R9 feed-side nulls |
// R10 plain scattered 148 | R11 plain seq-block 154.
// R12: the last untested cell -- plain stores x CONTIGUOUS DEVICE-WIDE
// FRONT. Fill is grid-stride: all waves write one sliding ~4MB window.
// Every previous variant partitioned adj by image -> scattered front.
// Two kernels: prepass computes qn (25.7MB, L2-resident) into d_ws +
// logits; streamer grid-strides flat over adj exactly like fill.
// Pre-commit: >=135us -> revert to R8-NT and declare roofline.

#define NP    196
#define NPIX  784
#define BLK   256
#define VPR   (NP / 4)            // 49 float4 per row
#define F4PI  (NP * NP / 4)       // 9604 float4 per image
#define IMGB  8                   // images per prepass block

typedef float f32x4 __attribute__((ext_vector_type(4)));

// ---------------- kernel 1: qn prepass + logits ----------------
__global__ __launch_bounds__(BLK) void qn_prepass(
    const float* __restrict__ x,
    const float* __restrict__ W1, const float* __restrict__ b1,
    const float* __restrict__ W2, const float* __restrict__ b2,
    float* __restrict__ logits,
    float* __restrict__ qnA_g,     // [B][196][4]
    float* __restrict__ qnT_g)     // [B][4][196]
{
    __shared__ float q4[IMGB][NP][4];     // raw cos(q)
    __shared__ float pooled[IMGB][4];

    const int blk = blockIdx.x;
    const int tid = threadIdx.x;
    const int w   = tid >> 6;
    const int l   = tid & 63;
    const float* imgs = x + (size_t)blk * (IMGB * NPIX);

    // 1) load 8 images -> cos -> q in LDS
    for (int p = tid; p < IMGB * NPIX; p += BLK) {
        int im = p / NPIX;
        int pp = p - im * NPIX;
        int r = pp / 28;
        int c = pp - r * 28;
        int n  = (r >> 1) * 14 + (c >> 1);
        int dd = ((r & 1) << 1) | (c & 1);
        q4[im][n][dd] = cosf(imgs[p]);
    }
    __syncthreads();

    // 2) pooled = mean_n q; wave w handles images 2w, 2w+1
    for (int imw = 0; imw < 2; ++imw) {
        int im = 2 * w + imw;
        float s0 = 0.f, s1 = 0.f, s2 = 0.f, s3 = 0.f;
        for (int n = l; n < NP; n += 64) {
            s0 += q4[im][n][0]; s1 += q4[im][n][1];
            s2 += q4[im][n][2]; s3 += q4[im][n][3];
        }
        #pragma unroll
        for (int off = 32; off >= 1; off >>= 1) {
            s0 += __shfl_down(s0, off);
            s1 += __shfl_down(s1, off);
            s2 += __shfl_down(s2, off);
            s3 += __shfl_down(s3, off);
        }
        if (l == 0) {
            pooled[im][0] = s0 * (1.0f / NP);
            pooled[im][1] = s1 * (1.0f / NP);
            pooled[im][2] = s2 * (1.0f / NP);
            pooled[im][3] = s3 * (1.0f / NP);
        }
    }

    // 3) normalize -> global qnA (AoS) + qnT (dim-major)
    for (int t = tid; t < IMGB * NP; t += BLK) {
        int im = t / NP;
        int n  = t - im * NP;
        size_t gi = (size_t)(blk * IMGB + im);
        float a0 = q4[im][n][0], a1 = q4[im][n][1];
        float a2 = q4[im][n][2], a3 = q4[im][n][3];
        float inv = 1.0f / (sqrtf(a0*a0 + a1*a1 + a2*a2 + a3*a3) + 1e-12f);
        f32x4 v; v.x = a0*inv; v.y = a1*inv; v.z = a2*inv; v.w = a3*inv;
        *reinterpret_cast<f32x4*>(qnA_g + (gi * NP + n) * 4) = v;
        float* qt = qnT_g + gi * (4 * NP);
        qt[0*NP + n] = v.x;
        qt[1*NP + n] = v.y;
        qt[2*NP + n] = v.z;
        qt[3*NP + n] = v.w;
    }
    __syncthreads();

    // 4) MLP: threads 0..79 (8 images x 10 logits)
    if (tid < IMGB * 10) {
        int im = tid / 10;
        int j  = tid - im * 10;
        float p0 = pooled[im][0], p1 = pooled[im][1];
        float p2 = pooled[im][2], p3 = pooled[im][3];
        float acc = b2[j];
        #pragma unroll
        for (int k = 0; k < 32; ++k) {
            float h = b1[k] + p0 * W1[0*32 + k] + p1 * W1[1*32 + k]
                            + p2 * W1[2*32 + k] + p3 * W1[3*32 + k];
            acc += h * W2[k*10 + j];
        }
        logits[(size_t)(blk * IMGB + im) * 10 + j] = acc;
    }
}

// ---------------- kernel 2: fill-shaped adj streamer ----------------
__global__ __launch_bounds__(BLK) void adj_stream(
    const float* __restrict__ qnA_g,
    const float* __restrict__ qnT_g,
    float* __restrict__ adj,
    unsigned int totalF4)
{
    f32x4* out = reinterpret_cast<f32x4*>(adj);
    const unsigned int stride = gridDim.x * BLK;

    for (unsigned int e4 = blockIdx.x * BLK + threadIdx.x; e4 < totalF4;
         e4 += stride) {
        unsigned int b   = e4 / F4PI;            // magic-div (const)
        unsigned int rem = e4 - b * F4PI;
        unsigned int n   = rem / VPR;            // magic-div by 49
        unsigned int m0  = (rem - n * VPR) * 4;

        const f32x4 c = *reinterpret_cast<const f32x4*>(
            qnA_g + ((size_t)b * NP + n) * 4);
        const float* qt = qnT_g + (size_t)b * (4 * NP);
        f32x4 v0 = *reinterpret_cast<const f32x4*>(qt + 0*NP + m0);
        f32x4 v1 = *reinterpret_cast<const f32x4*>(qt + 1*NP + m0);
        f32x4 v2 = *reinterpret_cast<const f32x4*>(qt + 2*NP + m0);
        f32x4 v3 = *reinterpret_cast<const f32x4*>(qt + 3*NP + m0);

        f32x4 d = c.x*v0 + c.y*v1 + c.z*v2 + c.w*v3;
        f32x4 f = d * d;

        f32x4 o;
        o.x = (f.x >= 0.8f) ? 1.0f : ((f.x >= 0.5f) ? 0.5f : 0.0f);
        o.y = (f.y >= 0.8f) ? 1.0f : ((f.y >= 0.5f) ? 0.5f : 0.0f);
        o.z = (f.z >= 0.8f) ? 1.0f : ((f.z >= 0.5f) ? 0.5f : 0.0f);
        o.w = (f.w >= 0.8f) ? 1.0f : ((f.w >= 0.5f) ? 0.5f : 0.0f);

        o.x = (m0 + 0 == n) ? 0.0f : o.x;
        o.y = (m0 + 1 == n) ? 0.0f : o.y;
        o.z = (m0 + 2 == n) ? 0.0f : o.z;
        o.w = (m0 + 3 == n) ? 0.0f : o.w;

        out[e4] = o;    // plain store, contiguous device-wide front
    }
}

extern "C" void kernel_launch(void* const* d_in, const int* in_sizes, int n_in,
                              void* d_out, int out_size, void* d_ws, size_t ws_size,
                              hipStream_t stream) {
    const float* x  = (const float*)d_in[0];
    const float* W1 = (const float*)d_in[1];
    const float* b1 = (const float*)d_in[2];
    const float* W2 = (const float*)d_in[3];
    const float* b2 = (const float*)d_in[4];

    const int B = in_sizes[0] / NPIX;          // 4096
    float* logits = (float*)d_out;             // B*10
    float* adj    = logits + (size_t)B * 10;   // B*196*196

    // workspace: qnA [B][196][4] then qnT [B][4][196]  (25.7 MB total)
    float* qnA_g = (float*)d_ws;
    float* qnT_g = qnA_g + (size_t)B * NP * 4;

    qn_prepass<<<B / IMGB, BLK, 0, stream>>>(x, W1, b1, W2, b2,
                                             logits, qnA_g, qnT_g);

    const unsigned int totalF4 = (unsigned int)B * F4PI;   // 39,337,984
    adj_stream<<<1024, BLK, 0, stream>>>(qnA_g, qnT_g, adj, totalF4);
}

// Round 13
// 137.287 us; speedup vs baseline: 1.5889x; 1.5889x over previous
//
#include <hip/hip_runtime.h>
#include <math.h>

// QuanvolutionHybridGraphQL:
//   q   = cos(2x2 patches of 28x28 img)            -> (B,196,4)
//   qn  = q / (||q||_2 + 1e-12)
//   fid = (qn . qn^T)^2                             -> (B,196,196)
//   adj = fid>=0.8 ? 1 : fid>=0.5 ? 0.5 : 0 ; diag=0
//   logits = (mean_n q @ W1 + b1) @ W2 + b2         -> (B,10)
// adj 629MB fp32 -> HBM-write bound. FINAL (= R7, session best 137.5us,
// ~4.6 TB/s effective write BW).
// Full A/B matrix (R1-R12): float4 NT stores +28% vs scalar; NT beats
// plain in every front shape (plain: 148 scattered / 154 seq / 218
// grid-stride); alignment ~+2%; per-byte instruction cuts, occupancy
// caps, stream-count, contiguous-front all NULL. NT ~4.6 TB/s is the
// empirical ceiling for this compute-fed write stream (fill = 6.6 TB/s
// is a pure-store upper bound, not reachable with in-kernel compute).

#define NP    196
#define NPIX  784
#define BLK   256
#define VPR   (NP / 4)            // 49 float4 per row
#define F4PI  (NP * NP / 4)       // 9604 float4 per image
#define F4PP  (2 * F4PI)          // 19208 float4 per image pair

typedef float f32x4 __attribute__((ext_vector_type(4)));

__global__ __launch_bounds__(BLK) void quanv_kernel(
    const float* __restrict__ x,
    const float* __restrict__ W1, const float* __restrict__ b1,
    const float* __restrict__ W2, const float* __restrict__ b2,
    float* __restrict__ logits, float* __restrict__ adj)
{
    __shared__ float q4[2][NP][4];                   // q, patch-major
    __shared__ __align__(16) float qnT[2][4][NP];    // qn, dim-major
    __shared__ float pooled[2][4];

    const int g   = blockIdx.x;        // image pair index
    const int tid = threadIdx.x;
    const int w   = tid >> 6;          // wave 0..3
    const int l   = tid & 63;          // lane 0..63
    const float* imgs = x + (size_t)g * (2 * NPIX);

    // 1) coalesced pixel load (both images) -> cos -> q in LDS
    for (int p = tid; p < 2 * NPIX; p += BLK) {
        int im = (p >= NPIX);
        int pp = p - im * NPIX;
        int r = pp / 28;
        int c = pp - r * 28;
        int n  = (r >> 1) * 14 + (c >> 1);
        int dd = ((r & 1) << 1) | (c & 1);
        q4[im][n][dd] = cosf(imgs[p]);
    }
    __syncthreads();

    // 2) per-patch L2-normalize into dim-major layout (strided: 392 > 256)
    for (int t = tid; t < 2 * NP; t += BLK) {
        int im = (t >= NP);
        int n  = t - im * NP;
        float a0 = q4[im][n][0], a1 = q4[im][n][1];
        float a2 = q4[im][n][2], a3 = q4[im][n][3];
        float inv = 1.0f / (sqrtf(a0*a0 + a1*a1 + a2*a2 + a3*a3) + 1e-12f);
        qnT[im][0][n] = a0 * inv;
        qnT[im][1][n] = a1 * inv;
        qnT[im][2][n] = a2 * inv;
        qnT[im][3][n] = a3 * inv;
    }

    // 3) pooled = mean_n q  (wave 0 -> image 0, wave 1 -> image 1)
    if (w < 2) {
        float s0 = 0.f, s1 = 0.f, s2 = 0.f, s3 = 0.f;
        for (int n = l; n < NP; n += 64) {
            s0 += q4[w][n][0]; s1 += q4[w][n][1];
            s2 += q4[w][n][2]; s3 += q4[w][n][3];
        }
        #pragma unroll
        for (int off = 32; off >= 1; off >>= 1) {
            s0 += __shfl_down(s0, off);
            s1 += __shfl_down(s1, off);
            s2 += __shfl_down(s2, off);
            s3 += __shfl_down(s3, off);
        }
        if (l == 0) {
            pooled[w][0] = s0 * (1.0f / NP);
            pooled[w][1] = s1 * (1.0f / NP);
            pooled[w][2] = s2 * (1.0f / NP);
            pooled[w][3] = s3 * (1.0f / NP);
        }
    }
    __syncthreads();

    // 4) tiny MLP for both images: threads 0..9 -> im 0, 10..19 -> im 1
    if (tid < 20) {
        int im = (tid >= 10);
        int j  = tid - im * 10;
        float p0 = pooled[im][0], p1 = pooled[im][1];
        float p2 = pooled[im][2], p3 = pooled[im][3];
        float acc = b2[j];
        #pragma unroll
        for (int k = 0; k < 32; ++k) {
            float h = b1[k] + p0 * W1[0*32 + k] + p1 * W1[1*32 + k]
                            + p2 * W1[2*32 + k] + p3 * W1[3*32 + k];
            acc += h * W2[k*10 + j];
        }
        logits[(size_t)(2*g + im) * 10 + j] = acc;
    }

    // 5) adj for the pair: flat loop, every wave store = aligned 1KiB NT.
    f32x4* outp = reinterpret_cast<f32x4*>(adj) + (size_t)g * F4PP;
    for (int e4 = tid; e4 < F4PP; e4 += BLK) {
        int im  = (e4 >= F4PI);
        int rem = e4 - im * F4PI;
        int n   = rem / VPR;               // magic-div by 49
        int m0  = (rem - n * VPR) * 4;

        float c0 = qnT[im][0][n], c1 = qnT[im][1][n];
        float c2 = qnT[im][2][n], c3 = qnT[im][3][n];
        f32x4 v0 = *reinterpret_cast<const f32x4*>(&qnT[im][0][m0]);
        f32x4 v1 = *reinterpret_cast<const f32x4*>(&qnT[im][1][m0]);
        f32x4 v2 = *reinterpret_cast<const f32x4*>(&qnT[im][2][m0]);
        f32x4 v3 = *reinterpret_cast<const f32x4*>(&qnT[im][3][m0]);

        f32x4 d = c0*v0 + c1*v1 + c2*v2 + c3*v3;
        f32x4 f = d * d;

        f32x4 o;
        o.x = (f.x >= 0.8f) ? 1.0f : ((f.x >= 0.5f) ? 0.5f : 0.0f);
        o.y = (f.y >= 0.8f) ? 1.0f : ((f.y >= 0.5f) ? 0.5f : 0.0f);
        o.z = (f.z >= 0.8f) ? 1.0f : ((f.z >= 0.5f) ? 0.5f : 0.0f);
        o.w = (f.w >= 0.8f) ? 1.0f : ((f.w >= 0.5f) ? 0.5f : 0.0f);

        // zero the diagonal element (column n) if it's in this float4
        o.x = (m0 + 0 == n) ? 0.0f : o.x;
        o.y = (m0 + 1 == n) ? 0.0f : o.y;
        o.z = (m0 + 2 == n) ? 0.0f : o.z;
        o.w = (m0 + 3 == n) ? 0.0f : o.w;

        __builtin_nontemporal_store(o, &outp[e4]);
    }
}

extern "C" void kernel_launch(void* const* d_in, const int* in_sizes, int n_in,
                              void* d_out, int out_size, void* d_ws, size_t ws_size,
                              hipStream_t stream) {
    const float* x  = (const float*)d_in[0];
    const float* W1 = (const float*)d_in[1];
    const float* b1 = (const float*)d_in[2];
    const float* W2 = (const float*)d_in[3];
    const float* b2 = (const float*)d_in[4];

    const int B = in_sizes[0] / NPIX;          // 4096
    float* logits = (float*)d_out;             // B*10
    float* adj    = logits + (size_t)B * 10;   // B*196*196

    quanv_kernel<<<B / 2, BLK, 0, stream>>>(x, W1, b1, W2, b2, logits, adj);
}